// Round 5
// baseline (145.856 us; speedup 1.0000x reference)
//
#include <hip/hip_runtime.h>
#include <hip/hip_bf16.h>

// Problem constants
#define B_    2
#define T_    2048
#define C_    1024
#define H_    16
#define D_    64
#define SRCL_ 128

typedef short  short8 __attribute__((ext_vector_type(8)));   // 8 bf16 (4 VGPRs)
typedef float  f32x4  __attribute__((ext_vector_type(4)));
typedef unsigned short ushort4_t __attribute__((ext_vector_type(4)));
typedef unsigned int   uint4v    __attribute__((ext_vector_type(4)));

// Q pre-scale: 0.125 (1/sqrt(64)) * log2(e) so attn can use raw v_exp_f32 (2^x)
#define QSCALE 0.18033688011112042f

__device__ inline unsigned short f2bf(float f) {
    union { float f; unsigned u; } v; v.f = f;
    unsigned r = v.u + 0x7FFFu + ((v.u >> 16) & 1u);   // RNE
    return (unsigned short)(r >> 16);
}

#if __has_builtin(__builtin_amdgcn_exp2f)
#define EXP2F(x) __builtin_amdgcn_exp2f(x)
#else
#define EXP2F(x) exp2f(x)
#endif

// async global->LDS DMA, 16B per lane; LDS dest = uniform base + lane*16
__device__ __forceinline__ void async_ld16(const void* g, void* l) {
    __builtin_amdgcn_global_load_lds(
        (const __attribute__((address_space(1))) unsigned int*)g,
        (__attribute__((address_space(3))) unsigned int*)l, 16, 0, 0);
}

// ---------------------------------------------------------------------------
// Kernel 1: fp32 -> bf16 conversion of x and the three weight matrices.
// ---------------------------------------------------------------------------
__global__ __launch_bounds__(256) void convert_all(
        const float* __restrict__ x,
        const float* __restrict__ wq,
        const float* __restrict__ wk,
        const float* __restrict__ wv,
        unsigned short* __restrict__ xb,
        unsigned short* __restrict__ wb)
{
    const int NX = (B_ * T_ * C_) / 4;
    const int NW = (C_ * C_) / 4;
    int i = blockIdx.x * 256 + threadIdx.x;
    const float4* src;
    ushort4_t* dst;
    if (i < NX)               { src = (const float4*)x;  dst = (ushort4_t*)xb;                }
    else if (i < NX + NW)     { src = (const float4*)wq; dst = (ushort4_t*)wb;                i -= NX; }
    else if (i < NX + 2*NW)   { src = (const float4*)wk; dst = (ushort4_t*)(wb + C_*C_);      i -= NX + NW; }
    else                      { src = (const float4*)wv; dst = (ushort4_t*)(wb + 2*C_*C_);    i -= NX + 2*NW; }
    float4 v = src[i];
    ushort4_t o;
    o.x = f2bf(v.x); o.y = f2bf(v.y); o.z = f2bf(v.z); o.w = f2bf(v.w);
    dst[i] = o;
}

// ---------------------------------------------------------------------------
// Kernel 2: fused QKV projection GEMM (round-1 config, best measured).
//  - double-buffered global_load_lds staging, ONE barrier per K-step
//  - LDS union: epilogue stage overlaps the tile buffers (33 KB -> 4 blocks/CU)
//  - outputs chunk-tiled per (bh, 64-t-tile), 8KB tiles:
//      Q,K: [d-chunk 0..7][t 0..63][8 d]   (Q pre-scaled by QSCALE)
//      V:   permuted chunk layout matching attn's in-register P fragments:
//           t -> chunk c = ((t>>5)<<2)|((t>>2)&3), slot s = (((t>>4)&1)<<2)|(t&3)
// ---------------------------------------------------------------------------
__global__ __launch_bounds__(256, 4) void gemm_qkv(
        const unsigned short* __restrict__ xb,   // [4096,1024]
        const unsigned short* __restrict__ wb,   // [3072,1024]
        const float* __restrict__ bq,
        const float* __restrict__ bk,
        const float* __restrict__ bv,
        unsigned short* __restrict__ qo,
        unsigned short* __restrict__ kt,
        unsigned short* __restrict__ vt)
{
    // union: [buf0 A 8KB | buf0 B 8KB | buf1 A 8KB | buf1 B 8KB] (32KB)
    //        overlapped after the K-loop by 4 x 8320B per-wave epilogue stages
    __shared__ __align__(16) unsigned short uni[16640];      // 33,280 B

    const int tid  = threadIdx.x;
    const int wave = tid >> 6;
    const int lane = tid & 63;
    const int lane15 = lane & 15;
    const int quad   = lane >> 4;
    const int wm = wave >> 1;
    const int wn = wave & 1;
    const int m0 = (blockIdx.x & 31) * 128;
    const int n0 = (blockIdx.x >> 5) * 128;

    f32x4 acc[4][4];
#pragma unroll
    for (int mi = 0; mi < 4; ++mi)
#pragma unroll
        for (int ni = 0; ni < 4; ++ni)
            acc[mi][ni] = (f32x4){0.f, 0.f, 0.f, 0.f};

    // staging: 8 x 1KB chunks per matrix per K-step; wave w issues chunks 2w,2w+1
    const int c0   = wave * 2;
    const int rowi0 = 16 * c0 + (lane >> 2);
    const int rowi1 = 16 * (c0 + 1) + (lane >> 2);
    const int col8 = (lane & 3) * 8;

    const unsigned short* xrow0 = &xb[(m0 + rowi0) * 1024 + col8];
    const unsigned short* xrow1 = &xb[(m0 + rowi1) * 1024 + col8];
    const unsigned short* wrow0 = &wb[(n0 + rowi0) * 1024 + col8];
    const unsigned short* wrow1 = &wb[(n0 + rowi1) * 1024 + col8];

    // prologue: K-step 0 -> buf 0
    async_ld16(xrow0, &uni[c0 * 512]);
    async_ld16(xrow1, &uni[(c0 + 1) * 512]);
    async_ld16(wrow0, &uni[4096 + c0 * 512]);
    async_ld16(wrow1, &uni[4096 + (c0 + 1) * 512]);

    for (int it = 0; it < 32; ++it) {
        // all of this tile's DMAs done (own vmcnt(0) x all waves + barrier);
        // also proves every wave finished reading the OTHER buffer.
        __asm__ volatile("s_waitcnt vmcnt(0)\n\ts_barrier" ::: "memory");

        if (it + 1 < 32) {
            const int k1 = (it + 1) * 32;
            unsigned short* nb = &uni[((it + 1) & 1) * 8192];
            async_ld16(xrow0 + k1, &nb[c0 * 512]);
            async_ld16(xrow1 + k1, &nb[(c0 + 1) * 512]);
            async_ld16(wrow0 + k1, &nb[4096 + c0 * 512]);
            async_ld16(wrow1 + k1, &nb[4096 + (c0 + 1) * 512]);
        }

        const unsigned short* As = &uni[(it & 1) * 8192];
        const unsigned short* Bs = As + 4096;

        short8 a[4], bf[4];
#pragma unroll
        for (int mi = 0; mi < 4; ++mi)
            a[mi] = *(const short8*)&As[(wm * 64 + mi * 16 + lane15) * 32 + quad * 8];
#pragma unroll
        for (int ni = 0; ni < 4; ++ni)
            bf[ni] = *(const short8*)&Bs[(wn * 64 + ni * 16 + lane15) * 32 + quad * 8];
#pragma unroll
        for (int mi = 0; mi < 4; ++mi)
#pragma unroll
            for (int ni = 0; ni < 4; ++ni)
                acc[mi][ni] = __builtin_amdgcn_mfma_f32_16x16x32_bf16(a[mi], bf[ni], acc[mi][ni], 0, 0, 0);
    }

    __syncthreads();   // all waves done with tile buffers -> safe to overlay Es

    // ---- epilogue ----
    const int colbase = n0 + wn * 64;
    const int which   = colbase >> 10;            // 0=q 1=k 2=v (wave-uniform)
    const int jj0     = colbase & 1023;
    const int h       = jj0 >> 6;
    const int rowbase = m0 + wm * 64;
    const int bidx    = rowbase >> 11;
    const int t0      = rowbase & 2047;
    const size_t bh   = (size_t)bidx * H_ + h;
    const float* bias_p = (which == 0 ? bq : (which == 1 ? bk : bv)) + jj0;
    const float oscale  = (which == 0) ? QSCALE : 1.0f;

    unsigned short* stage = &uni[wave * 4160];    // 8 chunks x 520 elems

    if (which != 2) {
        // Q/K chunk-tiled: pos = (d>>3)*520 + t*8 + (d&7)
#pragma unroll
        for (int ni = 0; ni < 4; ++ni) {
            const float bias = bias_p[ni * 16 + lane15];
            const int d = ni * 16 + lane15;
            const int dbase = (d >> 3) * 520 + (d & 7);
#pragma unroll
            for (int mi = 0; mi < 4; ++mi)
#pragma unroll
                for (int r = 0; r < 4; ++r) {
                    const int tt = mi * 16 + quad * 4 + r;
                    stage[dbase + tt * 8] = f2bf((acc[mi][ni][r] + bias) * oscale);
                }
        }
    } else {
        // V permuted chunk-tiled: chunk c = (mi>>1)*4 + quad, slot s = (mi&1)*4 + r
#pragma unroll
        for (int ni = 0; ni < 4; ++ni) {
            const float bias = bias_p[ni * 16 + lane15];
            const int d = ni * 16 + lane15;
#pragma unroll
            for (int mi = 0; mi < 4; ++mi)
#pragma unroll
                for (int r = 0; r < 4; ++r) {
                    const int tt = mi * 16 + quad * 4 + r;
                    const int c  = ((tt >> 5) << 2) | ((tt >> 2) & 3);
                    const int s  = (((tt >> 4) & 1) << 2) | (tt & 3);
                    stage[c * 520 + d * 8 + s] = f2bf(acc[mi][ni][r] + bias);
                }
        }
    }

    unsigned short* gdst =
        (which == 0 ? qo : (which == 1 ? kt : vt)) + bh * (size_t)(T_ * D_) + (t0 >> 6) * 4096;

    // same-wave LDS in-order: no barrier needed before reading own stage
#pragma unroll
    for (int c = 0; c < 8; ++c) {
        *(short8*)&gdst[(c * 64 + lane) * 8] = *(const short8*)&stage[c * 520 + lane * 8];
    }
}

// ---------------------------------------------------------------------------
// Kernel 3: flash attention with PAIRED q-tiles for load balance.
// Grid 512 = (bh, pair p): block processes q-tile aH=31-p AND aL=p in ONE
// K/V staging loop (light's key range is a prefix of heavy's, so each staged
// tile serves both; kf/vf fragments are read once and feed 2x the MFMAs).
// Per-block work = ntH+ntL = 35..37 tile-units for every p -> near-perfect
// balance (old worst CU: 4x32=128 units; new: 2x37=74).
// P stays entirely in registers (permuted-V layout). 2 blocks/CU resident.
// ---------------------------------------------------------------------------
__global__ __launch_bounds__(256, 2) void attn(
        const unsigned short* __restrict__ qg,   // chunk-tiled Q (pre-scaled)
        const unsigned short* __restrict__ kg,   // chunk-tiled K
        const unsigned short* __restrict__ vg,   // permuted chunk-tiled V
        float* __restrict__ out)                 // [B,T,C] fp32
{
    __shared__ __align__(16) unsigned short stage[2][8192];  // [buf][K 8KB | V 8KB]

    const int tid  = threadIdx.x;
    const int wave = tid >> 6;
    const int lane = tid & 63;
    const int lane15 = lane & 15;
    const int quad   = lane >> 4;

    const int bh = blockIdx.x & 31;
    const int p  = blockIdx.x >> 5;              // pair index 0..15
    const int aH = 31 - p;                       // heavy q-tile
    const int aL = p;                            // light q-tile
    const int b  = bh >> 4;
    const int h  = bh & 15;
    const int i0H = aH * 64 + wave * 16;
    const int i0L = aL * 64 + wave * 16;

    const unsigned short* Q  = qg + (size_t)bh * T_ * D_;
    const unsigned short* KT = kg + (size_t)bh * T_ * D_;
    const unsigned short* VT = vg + (size_t)bh * T_ * D_;

    // Q fragments from chunk-tiled layout: [qtile][d-chunk][t][8d]
    const int qrow = wave * 16 + lane15;
    const short8 qfH0 = *(const short8*)&Q[aH * 4096 + quad * 512 + qrow * 8];
    const short8 qfH1 = *(const short8*)&Q[aH * 4096 + (4 + quad) * 512 + qrow * 8];
    const short8 qfL0 = *(const short8*)&Q[aL * 4096 + quad * 512 + qrow * 8];
    const short8 qfL1 = *(const short8*)&Q[aL * 4096 + (4 + quad) * 512 + qrow * 8];

    f32x4 oH[4], oL[4];
#pragma unroll
    for (int di = 0; di < 4; ++di) {
        oH[di] = (f32x4){0.f, 0.f, 0.f, 0.f};
        oL[di] = (f32x4){0.f, 0.f, 0.f, 0.f};
    }
    float lH = 0.f, lL = 0.f;

    const int ntH = min(aH + 3, 32);             // 19..32 (aH >= 16)
    const int ntL = aL + 3;                      // 3..18  (aL <= 15), ntL < ntH
    const int limH = i0H + lane15 + SRCL_;
    const int limL = i0L + lane15 + SRCL_;

    // DMA of one 16KB tile-pair: 16 x 1KB instrs; wave w issues instrs 4w..4w+3
    const int ib = wave * 4;
    const int loff = lane * 8;

    // prologue: tile 0 -> buf 0
#pragma unroll
    for (int c = 0; c < 4; ++c) {
        const int i = ib + c;
        const unsigned short* src = (i < 8) ? &KT[i * 512 + loff]
                                            : &VT[(i - 8) * 512 + loff];
        async_ld16(src, &stage[0][i * 512]);
    }

    for (int it = 0; it < ntH; ++it) {
        // own 4 DMAs done + all waves past compute of the other buffer
        __asm__ volatile("s_waitcnt vmcnt(0)\n\ts_barrier" ::: "memory");

        if (it + 1 < ntH) {
            unsigned short* nb = &stage[(it + 1) & 1][0];
            const size_t tb = (size_t)(it + 1) * 4096;
#pragma unroll
            for (int c = 0; c < 4; ++c) {
                const int i = ib + c;
                const unsigned short* src = (i < 8) ? &KT[tb + i * 512 + loff]
                                                    : &VT[tb + (i - 8) * 512 + loff];
                async_ld16(src, &nb[i * 512]);
            }
        }

        const unsigned short* sb = &stage[it & 1][0];
        const int j0 = it << 6;
        const bool lact = (it < ntL);            // light tile active this iter

        // ---- S^T = K Q^T for heavy (+light, sharing the kf reads)
        f32x4 svH[4], svL[4];
#pragma unroll
        for (int ni = 0; ni < 4; ++ni) {
            const short8 kf0 = *(const short8*)&sb[quad * 512 + (ni * 16 + lane15) * 8];
            const short8 kf1 = *(const short8*)&sb[(4 + quad) * 512 + (ni * 16 + lane15) * 8];
            f32x4 t = (f32x4){0.f, 0.f, 0.f, 0.f};
            t = __builtin_amdgcn_mfma_f32_16x16x32_bf16(kf0, qfH0, t, 0, 0, 0);
            t = __builtin_amdgcn_mfma_f32_16x16x32_bf16(kf1, qfH1, t, 0, 0, 0);
            svH[ni] = t;
            if (lact) {
                f32x4 u = (f32x4){0.f, 0.f, 0.f, 0.f};
                u = __builtin_amdgcn_mfma_f32_16x16x32_bf16(kf0, qfL0, u, 0, 0, 0);
                u = __builtin_amdgcn_mfma_f32_16x16x32_bf16(kf1, qfL1, u, 0, 0, 0);
                svL[ni] = u;
            }
        }

        if (j0 + 63 > i0H + SRCL_) {              // heavy boundary tiles only
#pragma unroll
            for (int ni = 0; ni < 4; ++ni)
#pragma unroll
                for (int r = 0; r < 4; ++r) {
                    const int key = j0 + ni * 16 + quad * 4 + r;
                    if (key > limH) svH[ni][r] = -INFINITY;
                }
        }
        if (lact && (j0 + 63 > i0L + SRCL_)) {    // light boundary tiles only
#pragma unroll
            for (int ni = 0; ni < 4; ++ni)
#pragma unroll
                for (int r = 0; r < 4; ++r) {
                    const int key = j0 + ni * 16 + quad * 4 + r;
                    if (key > limL) svL[ni][r] = -INFINITY;
                }
        }

        // ---- softmax numerators -> packed bf16 P fragments (in registers)
        // lane (quad,lane15) holds P^T[key = j0 + ni*16 + 4*quad + r][q=lane15];
        // pf0 element e -> key 16*(e>>2) + 4*quad + (e&3), pf1 -> +32.
        // V was stored (gemm epilogue) with exactly this t->(chunk,slot) map.
        short8 pfH0, pfH1, pfL0, pfL1;
        {
            float lacc = 0.f;
            unsigned pw[8];
#pragma unroll
            for (int ni = 0; ni < 4; ++ni) {
                const float p0 = EXP2F(svH[ni][0]);
                const float p1 = EXP2F(svH[ni][1]);
                const float p2 = EXP2F(svH[ni][2]);
                const float p3 = EXP2F(svH[ni][3]);
                lacc += (p0 + p1) + (p2 + p3);
                const unsigned u0 = __float_as_uint(p0) + 0x8000u;
                const unsigned u1 = __float_as_uint(p1) + 0x8000u;
                const unsigned u2 = __float_as_uint(p2) + 0x8000u;
                const unsigned u3 = __float_as_uint(p3) + 0x8000u;
                pw[ni * 2]     = __builtin_amdgcn_perm(u1, u0, 0x07060302);
                pw[ni * 2 + 1] = __builtin_amdgcn_perm(u3, u2, 0x07060302);
            }
            lH += lacc;
            const uint4v w0 = {pw[0], pw[1], pw[2], pw[3]};
            const uint4v w1 = {pw[4], pw[5], pw[6], pw[7]};
            pfH0 = __builtin_bit_cast(short8, w0);
            pfH1 = __builtin_bit_cast(short8, w1);
        }
        if (lact) {
            float lacc = 0.f;
            unsigned pw[8];
#pragma unroll
            for (int ni = 0; ni < 4; ++ni) {
                const float p0 = EXP2F(svL[ni][0]);
                const float p1 = EXP2F(svL[ni][1]);
                const float p2 = EXP2F(svL[ni][2]);
                const float p3 = EXP2F(svL[ni][3]);
                lacc += (p0 + p1) + (p2 + p3);
                const unsigned u0 = __float_as_uint(p0) + 0x8000u;
                const unsigned u1 = __float_as_uint(p1) + 0x8000u;
                const unsigned u2 = __float_as_uint(p2) + 0x8000u;
                const unsigned u3 = __float_as_uint(p3) + 0x8000u;
                pw[ni * 2]     = __builtin_amdgcn_perm(u1, u0, 0x07060302);
                pw[ni * 2 + 1] = __builtin_amdgcn_perm(u3, u2, 0x07060302);
            }
            lL += lacc;
            const uint4v w0 = {pw[0], pw[1], pw[2], pw[3]};
            const uint4v w1 = {pw[4], pw[5], pw[6], pw[7]};
            pfL0 = __builtin_bit_cast(short8, w0);
            pfL1 = __builtin_bit_cast(short8, w1);
        }

        // ---- V fragments (read once) + PV for heavy (+light)
#pragma unroll
        for (int di = 0; di < 4; ++di) {
            const short8 vf0 = *(const short8*)&sb[4096 + quad * 512 + (di * 16 + lane15) * 8];
            const short8 vf1 = *(const short8*)&sb[4096 + (4 + quad) * 512 + (di * 16 + lane15) * 8];
            oH[di] = __builtin_amdgcn_mfma_f32_16x16x32_bf16(vf0, pfH0, oH[di], 0, 0, 0);
            oH[di] = __builtin_amdgcn_mfma_f32_16x16x32_bf16(vf1, pfH1, oH[di], 0, 0, 0);
            if (lact) {
                oL[di] = __builtin_amdgcn_mfma_f32_16x16x32_bf16(vf0, pfL0, oL[di], 0, 0, 0);
                oL[di] = __builtin_amdgcn_mfma_f32_16x16x32_bf16(vf1, pfL1, oL[di], 0, 0, 0);
            }
        }
    }

    __syncthreads();   // stage reuse as O scratch across waves

    float s0 = lH + __shfl_xor(lH, 16);
    const float invH = 1.0f / (s0 + __shfl_xor(s0, 32));
    float s1 = lL + __shfl_xor(lL, 16);
    const float invL = 1.0f / (s1 + __shfl_xor(s1, 32));

    float* myOs = (float*)&stage[0][0] + wave * 2048;   // 8KB per wave, private

    // ---- heavy tile output
#pragma unroll
    for (int di = 0; di < 4; ++di) {
        f32x4 v = oH[di] * invH;
        *(f32x4*)&myOs[lane15 * 68 + di * 16 + quad * 4] = v;   // [q][d]
    }
    float* orowH = out + ((size_t)(b * T_ + i0H)) * C_ + h * 64;
#pragma unroll
    for (int c = 0; c < 4; ++c) {
        const int idx = c * 64 + lane;
        const int t   = idx >> 4;
        const int dc  = (idx & 15) * 4;
        float4 v = *(float4*)&myOs[t * 68 + dc];
        *(float4*)(orowH + (size_t)t * C_ + dc) = v;
    }

    // ---- light tile output (same-wave LDS region reuse; in-order)
#pragma unroll
    for (int di = 0; di < 4; ++di) {
        f32x4 v = oL[di] * invL;
        *(f32x4*)&myOs[lane15 * 68 + di * 16 + quad * 4] = v;
    }
    float* orowL = out + ((size_t)(b * T_ + i0L)) * C_ + h * 64;
#pragma unroll
    for (int c = 0; c < 4; ++c) {
        const int idx = c * 64 + lane;
        const int t   = idx >> 4;
        const int dc  = (idx & 15) * 4;
        float4 v = *(float4*)&myOs[t * 68 + dc];
        *(float4*)(orowL + (size_t)t * C_ + dc) = v;
    }
}

// ---------------------------------------------------------------------------
// Launch
// ---------------------------------------------------------------------------
extern "C" void kernel_launch(void* const* d_in, const int* in_sizes, int n_in,
                              void* d_out, int out_size, void* d_ws, size_t ws_size,
                              hipStream_t stream) {
    const float* x  = (const float*)d_in[0];
    const float* Wq = (const float*)d_in[1];
    const float* bq = (const float*)d_in[2];
    const float* Wk = (const float*)d_in[3];
    const float* bk = (const float*)d_in[4];
    const float* Wv = (const float*)d_in[5];
    const float* bv = (const float*)d_in[6];
    float* out = (float*)d_out;

    unsigned short* xb  = (unsigned short*)d_ws;            // 4096*1024
    unsigned short* wb  = xb  + (size_t)B_ * T_ * C_;       // 3*1024*1024
    unsigned short* qb  = wb  + (size_t)3 * C_ * C_;        // chunk-tiled Q
    unsigned short* ktb = qb  + (size_t)B_ * H_ * T_ * D_;  // chunk-tiled K
    unsigned short* vtb = ktb + (size_t)B_ * H_ * T_ * D_;  // permuted chunk-tiled V

    convert_all<<<7168, 256, 0, stream>>>(x, Wq, Wk, Wv, xb, wb);
    gemm_qkv<<<768, 256, 0, stream>>>(xb, wb, bq, bk, bv, qb, ktb, vtb);
    attn<<<512, 256, 0, stream>>>(qb, ktb, vtb, out);
}

// Round 6
// 145.371 us; speedup vs baseline: 1.0033x; 1.0033x over previous
//
#include <hip/hip_runtime.h>
#include <hip/hip_bf16.h>

// Problem constants
#define B_    2
#define T_    2048
#define C_    1024
#define H_    16
#define D_    64
#define SRCL_ 128

typedef short  short8 __attribute__((ext_vector_type(8)));   // 8 bf16 (4 VGPRs)
typedef float  f32x4  __attribute__((ext_vector_type(4)));
typedef unsigned short ushort4_t __attribute__((ext_vector_type(4)));
typedef unsigned int   uint4v    __attribute__((ext_vector_type(4)));

// Q pre-scale: 0.125 (1/sqrt(64)) * log2(e) so attn can use raw v_exp_f32 (2^x)
#define QSCALE 0.18033688011112042f

__device__ inline unsigned short f2bf(float f) {
    union { float f; unsigned u; } v; v.f = f;
    unsigned r = v.u + 0x7FFFu + ((v.u >> 16) & 1u);   // RNE
    return (unsigned short)(r >> 16);
}

#if __has_builtin(__builtin_amdgcn_exp2f)
#define EXP2F(x) __builtin_amdgcn_exp2f(x)
#else
#define EXP2F(x) exp2f(x)
#endif

// async global->LDS DMA, 16B per lane; LDS dest = uniform base + lane*16
__device__ __forceinline__ void async_ld16(const void* g, void* l) {
    __builtin_amdgcn_global_load_lds(
        (const __attribute__((address_space(1))) unsigned int*)g,
        (__attribute__((address_space(3))) unsigned int*)l, 16, 0, 0);
}

// ---------------------------------------------------------------------------
// Kernel 1: fp32 -> bf16 conversion of x and the three weight matrices.
// ---------------------------------------------------------------------------
__global__ __launch_bounds__(256) void convert_all(
        const float* __restrict__ x,
        const float* __restrict__ wq,
        const float* __restrict__ wk,
        const float* __restrict__ wv,
        unsigned short* __restrict__ xb,
        unsigned short* __restrict__ wb)
{
    const int NX = (B_ * T_ * C_) / 4;
    const int NW = (C_ * C_) / 4;
    int i = blockIdx.x * 256 + threadIdx.x;
    const float4* src;
    ushort4_t* dst;
    if (i < NX)               { src = (const float4*)x;  dst = (ushort4_t*)xb;                }
    else if (i < NX + NW)     { src = (const float4*)wq; dst = (ushort4_t*)wb;                i -= NX; }
    else if (i < NX + 2*NW)   { src = (const float4*)wk; dst = (ushort4_t*)(wb + C_*C_);      i -= NX + NW; }
    else                      { src = (const float4*)wv; dst = (ushort4_t*)(wb + 2*C_*C_);    i -= NX + 2*NW; }
    float4 v = src[i];
    ushort4_t o;
    o.x = f2bf(v.x); o.y = f2bf(v.y); o.z = f2bf(v.z); o.w = f2bf(v.w);
    dst[i] = o;
}

// ---------------------------------------------------------------------------
// Kernel 2: fused QKV projection GEMM — 256x256 tile, BK=64, counted vmcnt.
//  - 512 threads = 8 waves (2M x 4N); per-wave output 128x64; acc[8][4].
//  - LDS 128KB: 2 bufs x [A 32KB | B 32KB]; each k-half-32 is a [256][32]
//    row-major subtile (A: kk*16KB, B: 32KB + kk*16KB).
//  - Staging: per K-tile split into S0 (k-cols 0..31 of A+B) and S1
//    (k-cols 32..63). Waves 0-3 stage A rows (w&3)*64..+63, waves 4-7 the
//    same rows of B; 4 x global_load_lds (1KB) per wave per half.
//  - 2 phases per K-tile; per phase: vmcnt(4)+barrier retires exactly the
//    half needed NOW while the other 4 loads stay in flight (T4: never
//    drain to 0 in the loop); then issue next tile's half; ds_read frags;
//    32 MFMA. Counted-vmcnt pipelining is the whole point (m218).
//  - Grid 192 (16 Mt x 12 Nt), XCD-chunked: xcd=bid&7 owns M-panels
//    {2*xcd, 2*xcd+1} x all N -> A panel L2-resident per XCD.
//  - Epilogue: same chunk-tiled Q/K + permuted V as before, two 64-row
//    passes per wave, per-wave 8320B LDS stage overlay.
// ---------------------------------------------------------------------------
__global__ __launch_bounds__(512, 2) void gemm_qkv(
        const unsigned short* __restrict__ xb,   // [4096,1024]
        const unsigned short* __restrict__ wb,   // [3072,1024]
        const float* __restrict__ bq,
        const float* __restrict__ bk,
        const float* __restrict__ bv,
        unsigned short* __restrict__ qo,
        unsigned short* __restrict__ ktp,
        unsigned short* __restrict__ vtp)
{
    __shared__ __align__(16) unsigned short uni[65536];      // 131,072 B

    const int tid  = threadIdx.x;
    const int wave = tid >> 6;           // 0..7
    const int lane = tid & 63;
    const int lane15 = lane & 15;
    const int quad   = lane >> 4;
    const int wm = wave >> 2;            // 0..1  M-half
    const int wn = wave & 3;             // 0..3  N-quarter

    const int bid = blockIdx.x;
    const int xcd = bid & 7;
    const int jj  = bid >> 3;            // 0..23
    const int mt  = xcd * 2 + (jj / 12); // 0..15
    const int nt  = jj % 12;             // 0..11
    const int m0 = mt * 256;
    const int n0 = nt * 256;

    f32x4 acc[8][4];
#pragma unroll
    for (int m = 0; m < 8; ++m)
#pragma unroll
        for (int n = 0; n < 4; ++n)
            acc[m][n] = (f32x4){0.f, 0.f, 0.f, 0.f};

    // staging geometry: waves 0-3 stage A, 4-7 stage B; each wave 4 x 1KB
    // instrs per half = 64 rows x 32 k-cols, 16 rows per instr.
    char* lds = (char*)uni;
    const unsigned short* gb = (wave < 4) ? (xb + (size_t)m0 * 1024)
                                          : (wb + (size_t)n0 * 1024);
    const unsigned short* gsrc =
        gb + ((wave & 3) * 64 + (lane >> 2)) * 1024 + (lane & 3) * 8;
    const int lbase0 = ((wave < 4) ? 0 : 32768) + (wave & 3) * 4096;

    auto stage = [&](int t2, int kk) {
        char* ld = lds + (t2 & 1) * 65536 + lbase0 + kk * 16384;
        const unsigned short* gs = gsrc + t2 * 64 + kk * 32;
        async_ld16(gs,             ld);
        async_ld16(gs + 16 * 1024, ld + 1024);
        async_ld16(gs + 32 * 1024, ld + 2048);
        async_ld16(gs + 48 * 1024, ld + 3072);
    };

    auto compute = [&](int cur, int kk) {
        const char* ab = lds + cur * 65536 + kk * 16384;
        const char* bb = ab + 32768;
        short8 a[8], b[4];
#pragma unroll
        for (int n = 0; n < 4; ++n)
            b[n] = *(const short8*)(bb + (wn * 64 + n * 16 + lane15) * 64 + quad * 16);
#pragma unroll
        for (int m = 0; m < 8; ++m)
            a[m] = *(const short8*)(ab + (wm * 128 + m * 16 + lane15) * 64 + quad * 16);
#pragma unroll
        for (int m = 0; m < 8; ++m)
#pragma unroll
            for (int n = 0; n < 4; ++n)
                acc[m][n] = __builtin_amdgcn_mfma_f32_16x16x32_bf16(a[m], b[n], acc[m][n], 0, 0, 0);
    };

    // prologue: tile 0 fully staged (8 loads/wave outstanding)
    stage(0, 0);
    stage(0, 1);

    for (int t = 0; t < 16; ++t) {
        const int cur = t & 1;
        // phase 0: retire S0(t) (own oldest 4), keep S1(t) in flight;
        // barrier also frees buf[cur^1] kk0 region (last read 2 barriers ago)
        __asm__ volatile("s_waitcnt vmcnt(4)\n\ts_barrier" ::: "memory");
        if (t < 15) stage(t + 1, 0);
        compute(cur, 0);
        // phase 1: retire S1(t), keep S0(t+1) in flight (drain only at end)
        if (t < 15) {
            __asm__ volatile("s_waitcnt vmcnt(4)\n\ts_barrier" ::: "memory");
            stage(t + 1, 1);
        } else {
            __asm__ volatile("s_waitcnt vmcnt(0)\n\ts_barrier" ::: "memory");
        }
        compute(cur, 1);
    }

    __syncthreads();   // all waves done with tile buffers -> overlay stages

    // ---- epilogue: two 64-row passes per wave ----
    const int colbase = n0 + wn * 64;
    const int which   = colbase >> 10;            // 0=q 1=k 2=v (wave-uniform)
    const int jj0     = colbase & 1023;
    const int h       = jj0 >> 6;
    const float* bias_p = (which == 0 ? bq : (which == 1 ? bk : bv)) + jj0;
    const float oscale  = (which == 0) ? QSCALE : 1.0f;

    unsigned short* stg = &uni[wave * 4160];      // 8 chunks x 520 elems

#pragma unroll
    for (int pass = 0; pass < 2; ++pass) {
        if (which != 2) {
            // Q/K chunk-tiled: pos = (d>>3)*520 + tt*8 + (d&7)
#pragma unroll
            for (int ni = 0; ni < 4; ++ni) {
                const float bias = bias_p[ni * 16 + lane15];
                const int d = ni * 16 + lane15;
                const int dbase = (d >> 3) * 520 + (d & 7);
#pragma unroll
                for (int mi = 0; mi < 4; ++mi)
#pragma unroll
                    for (int r = 0; r < 4; ++r) {
                        const int tt = mi * 16 + quad * 4 + r;
                        stg[dbase + tt * 8] =
                            f2bf((acc[pass * 4 + mi][ni][r] + bias) * oscale);
                    }
            }
        } else {
            // V permuted chunk-tiled: c=((tt>>5)<<2)|((tt>>2)&3),
            // s=(((tt>>4)&1)<<2)|(tt&3)  (matches attn's in-register P frags)
#pragma unroll
            for (int ni = 0; ni < 4; ++ni) {
                const float bias = bias_p[ni * 16 + lane15];
                const int d = ni * 16 + lane15;
#pragma unroll
                for (int mi = 0; mi < 4; ++mi)
#pragma unroll
                    for (int r = 0; r < 4; ++r) {
                        const int tt = mi * 16 + quad * 4 + r;
                        const int c  = ((tt >> 5) << 2) | ((tt >> 2) & 3);
                        const int s  = (((tt >> 4) & 1) << 2) | (tt & 3);
                        stg[c * 520 + d * 8 + s] =
                            f2bf(acc[pass * 4 + mi][ni][r] + bias);
                    }
            }
        }

        const int rowg = m0 + wm * 128 + pass * 64;
        const int bidx = rowg >> 11;
        const int t0   = rowg & 2047;
        const size_t bh = (size_t)bidx * H_ + h;
        unsigned short* gdst =
            (which == 0 ? qo : (which == 1 ? ktp : vtp))
            + bh * (size_t)(T_ * D_) + (t0 >> 6) * 4096;

        // same-wave LDS in-order: no barrier needed before reading own stage
#pragma unroll
        for (int c = 0; c < 8; ++c) {
            *(short8*)&gdst[(c * 64 + lane) * 8] = *(const short8*)&stg[c * 520 + lane * 8];
        }
    }
}

// ---------------------------------------------------------------------------
// Kernel 3: flash attention (round-1 config, best measured: 143.7us total).
// Block = (bh, 64 q-rows); 4 waves x 16 q-rows share staged K/V tiles.
// P stays entirely in registers: packed bf16 words feed PV's B operand
// directly; V's global layout (gemm epilogue) was permuted to match.
// LDS = 32KB -> 4 blocks/CU resident.
// ---------------------------------------------------------------------------
__global__ __launch_bounds__(256, 4) void attn(
        const unsigned short* __restrict__ qg,   // chunk-tiled Q (pre-scaled)
        const unsigned short* __restrict__ kg,   // chunk-tiled K
        const unsigned short* __restrict__ vg,   // permuted chunk-tiled V
        float* __restrict__ out)                 // [B,T,C] fp32
{
    __shared__ __align__(16) unsigned short stage[2][8192];  // [buf][K 8KB | V 8KB]

    const int tid  = threadIdx.x;
    const int wave = tid >> 6;
    const int lane = tid & 63;
    const int lane15 = lane & 15;
    const int quad   = lane >> 4;

    const int bh = blockIdx.x & 31;
    const int a  = 31 - (blockIdx.x >> 5);       // heavy q-blocks first
    const int b  = bh >> 4;
    const int h  = bh & 15;
    const int i0 = a * 64 + wave * 16;           // this wave's q rows

    const unsigned short* Q  = qg + (size_t)bh * T_ * D_;
    const unsigned short* KT = kg + (size_t)bh * T_ * D_;
    const unsigned short* VT = vg + (size_t)bh * T_ * D_;

    // Q fragments from chunk-tiled layout: [qtile a][d-chunk][t][8d]
    const int qrow = wave * 16 + lane15;
    const short8 qf0 = *(const short8*)&Q[a * 4096 + quad * 512 + qrow * 8];
    const short8 qf1 = *(const short8*)&Q[a * 4096 + (4 + quad) * 512 + qrow * 8];

    f32x4 o_acc[4];
#pragma unroll
    for (int di = 0; di < 4; ++di) o_acc[di] = (f32x4){0.f, 0.f, 0.f, 0.f};
    float l_p = 0.f;

    const int ntiles = min(a + 3, 32);           // key tiles for this q-block
    const int limit  = i0 + lane15 + SRCL_;

    // DMA of one 16KB tile-pair: 16 x 1KB instrs; wave w issues instrs 4w..4w+3
    const int ib = wave * 4;
    const int loff = lane * 8;

    // prologue: tile 0 -> buf 0
#pragma unroll
    for (int c = 0; c < 4; ++c) {
        const int i = ib + c;
        const unsigned short* src = (i < 8) ? &KT[i * 512 + loff]
                                            : &VT[(i - 8) * 512 + loff];
        async_ld16(src, &stage[0][i * 512]);
    }

    for (int it = 0; it < ntiles; ++it) {
        // own 4 DMAs done + all waves past compute of the other buffer
        __asm__ volatile("s_waitcnt vmcnt(0)\n\ts_barrier" ::: "memory");

        if (it + 1 < ntiles) {
            unsigned short* nb = &stage[(it + 1) & 1][0];
            const size_t tb = (size_t)(it + 1) * 4096;
#pragma unroll
            for (int c = 0; c < 4; ++c) {
                const int i = ib + c;
                const unsigned short* src = (i < 8) ? &KT[tb + i * 512 + loff]
                                                    : &VT[tb + (i - 8) * 512 + loff];
                async_ld16(src, &nb[i * 512]);
            }
        }

        const unsigned short* sb = &stage[it & 1][0];
        const int j0 = it << 6;

        // ---- S^T = K Q^T
        f32x4 sv[4];
#pragma unroll
        for (int ni = 0; ni < 4; ++ni) {
            const short8 kf0 = *(const short8*)&sb[quad * 512 + (ni * 16 + lane15) * 8];
            const short8 kf1 = *(const short8*)&sb[(4 + quad) * 512 + (ni * 16 + lane15) * 8];
            f32x4 t = (f32x4){0.f, 0.f, 0.f, 0.f};
            t = __builtin_amdgcn_mfma_f32_16x16x32_bf16(kf0, qf0, t, 0, 0, 0);
            t = __builtin_amdgcn_mfma_f32_16x16x32_bf16(kf1, qf1, t, 0, 0, 0);
            sv[ni] = t;
        }

        if (j0 + 63 > i0 + SRCL_) {               // boundary tiles only
#pragma unroll
            for (int ni = 0; ni < 4; ++ni)
#pragma unroll
                for (int r = 0; r < 4; ++r) {
                    const int key = j0 + ni * 16 + quad * 4 + r;
                    if (key > limit) sv[ni][r] = -INFINITY;
                }
        }

        // ---- softmax numerators -> packed bf16 P fragments (in registers)
        // lane (quad,lane15) holds P^T[key = j0 + ni*16 + 4*quad + r][q=lane15];
        // pf0 element e -> key 16*(e>>2) + 4*quad + (e&3), pf1 -> +32.
        // V was stored (gemm epilogue) with exactly this t->(chunk,slot) map.
        float lacc = 0.f;
        unsigned pw[8];
#pragma unroll
        for (int ni = 0; ni < 4; ++ni) {
            const float p0 = EXP2F(sv[ni][0]);
            const float p1 = EXP2F(sv[ni][1]);
            const float p2 = EXP2F(sv[ni][2]);
            const float p3 = EXP2F(sv[ni][3]);
            lacc += (p0 + p1) + (p2 + p3);
            const unsigned u0 = __float_as_uint(p0) + 0x8000u;
            const unsigned u1 = __float_as_uint(p1) + 0x8000u;
            const unsigned u2 = __float_as_uint(p2) + 0x8000u;
            const unsigned u3 = __float_as_uint(p3) + 0x8000u;
            pw[ni * 2]     = __builtin_amdgcn_perm(u1, u0, 0x07060302);
            pw[ni * 2 + 1] = __builtin_amdgcn_perm(u3, u2, 0x07060302);
        }
        l_p += lacc;

        const uint4v w0 = {pw[0], pw[1], pw[2], pw[3]};
        const uint4v w1 = {pw[4], pw[5], pw[6], pw[7]};
        const short8 pf0 = __builtin_bit_cast(short8, w0);
        const short8 pf1 = __builtin_bit_cast(short8, w1);

        // ---- V fragments + PV
#pragma unroll
        for (int di = 0; di < 4; ++di) {
            const short8 vf0 = *(const short8*)&sb[4096 + quad * 512 + (di * 16 + lane15) * 8];
            const short8 vf1 = *(const short8*)&sb[4096 + (4 + quad) * 512 + (di * 16 + lane15) * 8];
            o_acc[di] = __builtin_amdgcn_mfma_f32_16x16x32_bf16(vf0, pf0, o_acc[di], 0, 0, 0);
            o_acc[di] = __builtin_amdgcn_mfma_f32_16x16x32_bf16(vf1, pf1, o_acc[di], 0, 0, 0);
        }
    }

    __syncthreads();   // stage reuse as O scratch across waves

    float l0s = l_p + __shfl_xor(l_p, 16);
    const float inv = 1.0f / (l0s + __shfl_xor(l0s, 32));

    float* myOs = (float*)&stage[0][0] + wave * 2048;   // 8KB per wave
#pragma unroll
    for (int di = 0; di < 4; ++di) {
        f32x4 v = o_acc[di] * inv;
        *(f32x4*)&myOs[lane15 * 68 + di * 16 + quad * 4] = v;   // [q][d]
    }
    float* orow0 = out + ((size_t)(b * T_ + i0)) * C_ + h * 64;
#pragma unroll
    for (int c = 0; c < 4; ++c) {
        const int idx = c * 64 + lane;
        const int t   = idx >> 4;
        const int dc  = (idx & 15) * 4;
        float4 v = *(float4*)&myOs[t * 68 + dc];
        *(float4*)(orow0 + (size_t)t * C_ + dc) = v;
    }
}

// ---------------------------------------------------------------------------
// Launch
// ---------------------------------------------------------------------------
extern "C" void kernel_launch(void* const* d_in, const int* in_sizes, int n_in,
                              void* d_out, int out_size, void* d_ws, size_t ws_size,
                              hipStream_t stream) {
    const float* x  = (const float*)d_in[0];
    const float* Wq = (const float*)d_in[1];
    const float* bq = (const float*)d_in[2];
    const float* Wk = (const float*)d_in[3];
    const float* bk = (const float*)d_in[4];
    const float* Wv = (const float*)d_in[5];
    const float* bv = (const float*)d_in[6];
    float* out = (float*)d_out;

    unsigned short* xb  = (unsigned short*)d_ws;            // 4096*1024
    unsigned short* wb  = xb  + (size_t)B_ * T_ * C_;       // 3*1024*1024
    unsigned short* qb  = wb  + (size_t)3 * C_ * C_;        // chunk-tiled Q
    unsigned short* ktb = qb  + (size_t)B_ * H_ * T_ * D_;  // chunk-tiled K
    unsigned short* vtb = ktb + (size_t)B_ * H_ * T_ * D_;  // permuted chunk-tiled V

    convert_all<<<7168, 256, 0, stream>>>(x, Wq, Wk, Wv, xb, wb);
    gemm_qkv<<<192, 512, 0, stream>>>(xb, wb, bq, bk, bv, qb, ktb, vtb);
    attn<<<1024, 256, 0, stream>>>(qb, ktb, vtb, out);
}

// Round 7
// 144.689 us; speedup vs baseline: 1.0081x; 1.0047x over previous
//
#include <hip/hip_runtime.h>
#include <hip/hip_bf16.h>

// Problem constants
#define B_    2
#define T_    2048
#define C_    1024
#define H_    16
#define D_    64
#define SRCL_ 128

typedef short  short8 __attribute__((ext_vector_type(8)));   // 8 bf16 (4 VGPRs)
typedef float  f32x4  __attribute__((ext_vector_type(4)));
typedef unsigned short ushort4_t __attribute__((ext_vector_type(4)));
typedef unsigned int   uint4v    __attribute__((ext_vector_type(4)));

// Q pre-scale: 0.125 (1/sqrt(64)) * log2(e) so attn can use raw v_exp_f32 (2^x)
#define QSCALE 0.18033688011112042f

__device__ inline unsigned short f2bf(float f) {
    union { float f; unsigned u; } v; v.f = f;
    unsigned r = v.u + 0x7FFFu + ((v.u >> 16) & 1u);   // RNE
    return (unsigned short)(r >> 16);
}

#if __has_builtin(__builtin_amdgcn_exp2f)
#define EXP2F(x) __builtin_amdgcn_exp2f(x)
#else
#define EXP2F(x) exp2f(x)
#endif

// async global->LDS DMA, 16B per lane; LDS dest = uniform base + lane*16
__device__ __forceinline__ void async_ld16(const void* g, void* l) {
    __builtin_amdgcn_global_load_lds(
        (const __attribute__((address_space(1))) unsigned int*)g,
        (__attribute__((address_space(3))) unsigned int*)l, 16, 0, 0);
}

// ---------------------------------------------------------------------------
// Kernel 1: fp32 -> bf16 conversion of x and the three weight matrices.
// ---------------------------------------------------------------------------
__global__ __launch_bounds__(256) void convert_all(
        const float* __restrict__ x,
        const float* __restrict__ wq,
        const float* __restrict__ wk,
        const float* __restrict__ wv,
        unsigned short* __restrict__ xb,
        unsigned short* __restrict__ wb)
{
    const int NX = (B_ * T_ * C_) / 4;
    const int NW = (C_ * C_) / 4;
    int i = blockIdx.x * 256 + threadIdx.x;
    const float4* src;
    ushort4_t* dst;
    if (i < NX)               { src = (const float4*)x;  dst = (ushort4_t*)xb;                }
    else if (i < NX + NW)     { src = (const float4*)wq; dst = (ushort4_t*)wb;                i -= NX; }
    else if (i < NX + 2*NW)   { src = (const float4*)wk; dst = (ushort4_t*)(wb + C_*C_);      i -= NX + NW; }
    else                      { src = (const float4*)wv; dst = (ushort4_t*)(wb + 2*C_*C_);    i -= NX + 2*NW; }
    float4 v = src[i];
    ushort4_t o;
    o.x = f2bf(v.x); o.y = f2bf(v.y); o.z = f2bf(v.z); o.w = f2bf(v.w);
    dst[i] = o;
}

// ---------------------------------------------------------------------------
// Kernel 2: fused QKV projection GEMM (R1 structure + LDS bank-conflict fix).
//  - double-buffered global_load_lds staging, ONE barrier per K-step
//  - NEW: tile bytes XOR-swizzled with the involution  b ^= ((b>>3)&0x30)
//    (16B slot ^= row bits 1:2).  Write side realized by PRE-SWIZZLING the
//    per-lane GLOBAL source segment (LDS dest stays linear, required by the
//    DMA); read side applies the same XOR on the frag slot.  Turns the
//    8-way bank conflict of the [row][32] layout (bank group (4r+quad)&7
//    hits only 2 groups across lane15) into 2-way (free).
//  - LDS union: epilogue stage overlaps the tile buffers (33 KB -> 4 blocks/CU)
//  - outputs chunk-tiled per (bh, 64-t-tile), 8KB tiles:
//      Q,K: [d-chunk 0..7][t 0..63][8 d]   (Q pre-scaled by QSCALE)
//      V:   permuted chunk layout matching attn's in-register P fragments:
//           t -> chunk c = ((t>>5)<<2)|((t>>2)&3), slot s = (((t>>4)&1)<<2)|(t&3)
// ---------------------------------------------------------------------------
__global__ __launch_bounds__(256, 4) void gemm_qkv(
        const unsigned short* __restrict__ xb,   // [4096,1024]
        const unsigned short* __restrict__ wb,   // [3072,1024]
        const float* __restrict__ bq,
        const float* __restrict__ bk,
        const float* __restrict__ bv,
        unsigned short* __restrict__ qo,
        unsigned short* __restrict__ kt,
        unsigned short* __restrict__ vt)
{
    // union: [buf0 A 8KB | buf0 B 8KB | buf1 A 8KB | buf1 B 8KB] (32KB)
    //        overlapped after the K-loop by 4 x 8320B per-wave epilogue stages
    __shared__ __align__(16) unsigned short uni[16640];      // 33,280 B

    const int tid  = threadIdx.x;
    const int wave = tid >> 6;
    const int lane = tid & 63;
    const int lane15 = lane & 15;
    const int quad   = lane >> 4;
    const int wm = wave >> 1;
    const int wn = wave & 1;
    const int m0 = (blockIdx.x & 31) * 128;
    const int n0 = (blockIdx.x >> 5) * 128;

    f32x4 acc[4][4];
#pragma unroll
    for (int mi = 0; mi < 4; ++mi)
#pragma unroll
        for (int ni = 0; ni < 4; ++ni)
            acc[mi][ni] = (f32x4){0.f, 0.f, 0.f, 0.f};

    // staging: 8 x 1KB chunks per matrix per K-step; wave w issues chunks 2w,2w+1
    // PRE-SWIZZLED global source: lane l fetches k-segment (l&3)^((l>>3)&3)
    // so that the LINEAR DMA write lands data where the swizzled read expects.
    const int c0   = wave * 2;
    const int rowi0 = 16 * c0 + (lane >> 2);
    const int rowi1 = 16 * (c0 + 1) + (lane >> 2);
    const int col8 = (((lane & 3) ^ ((lane >> 3) & 3))) * 8;

    const unsigned short* xrow0 = &xb[(m0 + rowi0) * 1024 + col8];
    const unsigned short* xrow1 = &xb[(m0 + rowi1) * 1024 + col8];
    const unsigned short* wrow0 = &wb[(n0 + rowi0) * 1024 + col8];
    const unsigned short* wrow1 = &wb[(n0 + rowi1) * 1024 + col8];

    // prologue: K-step 0 -> buf 0
    async_ld16(xrow0, &uni[c0 * 512]);
    async_ld16(xrow1, &uni[(c0 + 1) * 512]);
    async_ld16(wrow0, &uni[4096 + c0 * 512]);
    async_ld16(wrow1, &uni[4096 + (c0 + 1) * 512]);

    // swizzled read slot for fragment loads (same involution as write side)
    const int slotA = (quad ^ ((lane15 >> 1) & 3)) * 8;

    for (int it = 0; it < 32; ++it) {
        // all of this tile's DMAs done (own vmcnt(0) x all waves + barrier);
        // also proves every wave finished reading the OTHER buffer.
        __asm__ volatile("s_waitcnt vmcnt(0)\n\ts_barrier" ::: "memory");

        if (it + 1 < 32) {
            const int k1 = (it + 1) * 32;
            unsigned short* nb = &uni[((it + 1) & 1) * 8192];
            async_ld16(xrow0 + k1, &nb[c0 * 512]);
            async_ld16(xrow1 + k1, &nb[(c0 + 1) * 512]);
            async_ld16(wrow0 + k1, &nb[4096 + c0 * 512]);
            async_ld16(wrow1 + k1, &nb[4096 + (c0 + 1) * 512]);
        }

        const unsigned short* As = &uni[(it & 1) * 8192];
        const unsigned short* Bs = As + 4096;

        short8 a[4], bf[4];
#pragma unroll
        for (int mi = 0; mi < 4; ++mi)
            a[mi] = *(const short8*)&As[(wm * 64 + mi * 16 + lane15) * 32 + slotA];
#pragma unroll
        for (int ni = 0; ni < 4; ++ni)
            bf[ni] = *(const short8*)&Bs[(wn * 64 + ni * 16 + lane15) * 32 + slotA];
#pragma unroll
        for (int mi = 0; mi < 4; ++mi)
#pragma unroll
            for (int ni = 0; ni < 4; ++ni)
                acc[mi][ni] = __builtin_amdgcn_mfma_f32_16x16x32_bf16(a[mi], bf[ni], acc[mi][ni], 0, 0, 0);
    }

    __syncthreads();   // all waves done with tile buffers -> safe to overlay Es

    // ---- epilogue ----
    const int colbase = n0 + wn * 64;
    const int which   = colbase >> 10;            // 0=q 1=k 2=v (wave-uniform)
    const int jj0     = colbase & 1023;
    const int h       = jj0 >> 6;
    const int rowbase = m0 + wm * 64;
    const int bidx    = rowbase >> 11;
    const int t0      = rowbase & 2047;
    const size_t bh   = (size_t)bidx * H_ + h;
    const float* bias_p = (which == 0 ? bq : (which == 1 ? bk : bv)) + jj0;
    const float oscale  = (which == 0) ? QSCALE : 1.0f;

    unsigned short* stage = &uni[wave * 4160];    // 8 chunks x 520 elems

    if (which != 2) {
        // Q/K chunk-tiled: pos = (d>>3)*520 + t*8 + (d&7)
#pragma unroll
        for (int ni = 0; ni < 4; ++ni) {
            const float bias = bias_p[ni * 16 + lane15];
            const int d = ni * 16 + lane15;
            const int dbase = (d >> 3) * 520 + (d & 7);
#pragma unroll
            for (int mi = 0; mi < 4; ++mi)
#pragma unroll
                for (int r = 0; r < 4; ++r) {
                    const int tt = mi * 16 + quad * 4 + r;
                    stage[dbase + tt * 8] = f2bf((acc[mi][ni][r] + bias) * oscale);
                }
        }
    } else {
        // V permuted chunk-tiled: chunk c = (mi>>1)*4 + quad, slot s = (mi&1)*4 + r
#pragma unroll
        for (int ni = 0; ni < 4; ++ni) {
            const float bias = bias_p[ni * 16 + lane15];
            const int d = ni * 16 + lane15;
#pragma unroll
            for (int mi = 0; mi < 4; ++mi)
#pragma unroll
                for (int r = 0; r < 4; ++r) {
                    const int tt = mi * 16 + quad * 4 + r;
                    const int c  = ((tt >> 5) << 2) | ((tt >> 2) & 3);
                    const int s  = (((tt >> 4) & 1) << 2) | (tt & 3);
                    stage[c * 520 + d * 8 + s] = f2bf(acc[mi][ni][r] + bias);
                }
        }
    }

    unsigned short* gdst =
        (which == 0 ? qo : (which == 1 ? kt : vt)) + bh * (size_t)(T_ * D_) + (t0 >> 6) * 4096;

    // same-wave LDS in-order: no barrier needed before reading own stage
#pragma unroll
    for (int c = 0; c < 8; ++c) {
        *(short8*)&gdst[(c * 64 + lane) * 8] = *(const short8*)&stage[c * 520 + lane * 8];
    }
}

// ---------------------------------------------------------------------------
// Kernel 3: flash attention (round-1 config, best measured: 143.7us total).
// Block = (bh, 64 q-rows); 4 waves x 16 q-rows share staged K/V tiles.
// P stays entirely in registers: packed bf16 words feed PV's B operand
// directly; V's global layout (gemm epilogue) was permuted to match.
// LDS = 32KB -> 4 blocks/CU resident.
// ---------------------------------------------------------------------------
__global__ __launch_bounds__(256, 4) void attn(
        const unsigned short* __restrict__ qg,   // chunk-tiled Q (pre-scaled)
        const unsigned short* __restrict__ kg,   // chunk-tiled K
        const unsigned short* __restrict__ vg,   // permuted chunk-tiled V
        float* __restrict__ out)                 // [B,T,C] fp32
{
    __shared__ __align__(16) unsigned short stage[2][8192];  // [buf][K 8KB | V 8KB]

    const int tid  = threadIdx.x;
    const int wave = tid >> 6;
    const int lane = tid & 63;
    const int lane15 = lane & 15;
    const int quad   = lane >> 4;

    const int bh = blockIdx.x & 31;
    const int a  = 31 - (blockIdx.x >> 5);       // heavy q-blocks first
    const int b  = bh >> 4;
    const int h  = bh & 15;
    const int i0 = a * 64 + wave * 16;           // this wave's q rows

    const unsigned short* Q  = qg + (size_t)bh * T_ * D_;
    const unsigned short* KT = kg + (size_t)bh * T_ * D_;
    const unsigned short* VT = vg + (size_t)bh * T_ * D_;

    // Q fragments from chunk-tiled layout: [qtile a][d-chunk][t][8d]
    const int qrow = wave * 16 + lane15;
    const short8 qf0 = *(const short8*)&Q[a * 4096 + quad * 512 + qrow * 8];
    const short8 qf1 = *(const short8*)&Q[a * 4096 + (4 + quad) * 512 + qrow * 8];

    f32x4 o_acc[4];
#pragma unroll
    for (int di = 0; di < 4; ++di) o_acc[di] = (f32x4){0.f, 0.f, 0.f, 0.f};
    float l_p = 0.f;

    const int ntiles = min(a + 3, 32);           // key tiles for this q-block
    const int limit  = i0 + lane15 + SRCL_;

    // DMA of one 16KB tile-pair: 16 x 1KB instrs; wave w issues instrs 4w..4w+3
    const int ib = wave * 4;
    const int loff = lane * 8;

    // prologue: tile 0 -> buf 0
#pragma unroll
    for (int c = 0; c < 4; ++c) {
        const int i = ib + c;
        const unsigned short* src = (i < 8) ? &KT[i * 512 + loff]
                                            : &VT[(i - 8) * 512 + loff];
        async_ld16(src, &stage[0][i * 512]);
    }

    for (int it = 0; it < ntiles; ++it) {
        // own 4 DMAs done + all waves past compute of the other buffer
        __asm__ volatile("s_waitcnt vmcnt(0)\n\ts_barrier" ::: "memory");

        if (it + 1 < ntiles) {
            unsigned short* nb = &stage[(it + 1) & 1][0];
            const size_t tb = (size_t)(it + 1) * 4096;
#pragma unroll
            for (int c = 0; c < 4; ++c) {
                const int i = ib + c;
                const unsigned short* src = (i < 8) ? &KT[tb + i * 512 + loff]
                                                    : &VT[tb + (i - 8) * 512 + loff];
                async_ld16(src, &nb[i * 512]);
            }
        }

        const unsigned short* sb = &stage[it & 1][0];
        const int j0 = it << 6;

        // ---- S^T = K Q^T
        f32x4 sv[4];
#pragma unroll
        for (int ni = 0; ni < 4; ++ni) {
            const short8 kf0 = *(const short8*)&sb[quad * 512 + (ni * 16 + lane15) * 8];
            const short8 kf1 = *(const short8*)&sb[(4 + quad) * 512 + (ni * 16 + lane15) * 8];
            f32x4 t = (f32x4){0.f, 0.f, 0.f, 0.f};
            t = __builtin_amdgcn_mfma_f32_16x16x32_bf16(kf0, qf0, t, 0, 0, 0);
            t = __builtin_amdgcn_mfma_f32_16x16x32_bf16(kf1, qf1, t, 0, 0, 0);
            sv[ni] = t;
        }

        if (j0 + 63 > i0 + SRCL_) {               // boundary tiles only
#pragma unroll
            for (int ni = 0; ni < 4; ++ni)
#pragma unroll
                for (int r = 0; r < 4; ++r) {
                    const int key = j0 + ni * 16 + quad * 4 + r;
                    if (key > limit) sv[ni][r] = -INFINITY;
                }
        }

        // ---- softmax numerators -> packed bf16 P fragments (in registers)
        // lane (quad,lane15) holds P^T[key = j0 + ni*16 + 4*quad + r][q=lane15];
        // pf0 element e -> key 16*(e>>2) + 4*quad + (e&3), pf1 -> +32.
        // V was stored (gemm epilogue) with exactly this t->(chunk,slot) map.
        float lacc = 0.f;
        unsigned pw[8];
#pragma unroll
        for (int ni = 0; ni < 4; ++ni) {
            const float p0 = EXP2F(sv[ni][0]);
            const float p1 = EXP2F(sv[ni][1]);
            const float p2 = EXP2F(sv[ni][2]);
            const float p3 = EXP2F(sv[ni][3]);
            lacc += (p0 + p1) + (p2 + p3);
            const unsigned u0 = __float_as_uint(p0) + 0x8000u;
            const unsigned u1 = __float_as_uint(p1) + 0x8000u;
            const unsigned u2 = __float_as_uint(p2) + 0x8000u;
            const unsigned u3 = __float_as_uint(p3) + 0x8000u;
            pw[ni * 2]     = __builtin_amdgcn_perm(u1, u0, 0x07060302);
            pw[ni * 2 + 1] = __builtin_amdgcn_perm(u3, u2, 0x07060302);
        }
        l_p += lacc;

        const uint4v w0 = {pw[0], pw[1], pw[2], pw[3]};
        const uint4v w1 = {pw[4], pw[5], pw[6], pw[7]};
        const short8 pf0 = __builtin_bit_cast(short8, w0);
        const short8 pf1 = __builtin_bit_cast(short8, w1);

        // ---- V fragments + PV
#pragma unroll
        for (int di = 0; di < 4; ++di) {
            const short8 vf0 = *(const short8*)&sb[4096 + quad * 512 + (di * 16 + lane15) * 8];
            const short8 vf1 = *(const short8*)&sb[4096 + (4 + quad) * 512 + (di * 16 + lane15) * 8];
            o_acc[di] = __builtin_amdgcn_mfma_f32_16x16x32_bf16(vf0, pf0, o_acc[di], 0, 0, 0);
            o_acc[di] = __builtin_amdgcn_mfma_f32_16x16x32_bf16(vf1, pf1, o_acc[di], 0, 0, 0);
        }
    }

    __syncthreads();   // stage reuse as O scratch across waves

    float l0s = l_p + __shfl_xor(l_p, 16);
    const float inv = 1.0f / (l0s + __shfl_xor(l0s, 32));

    float* myOs = (float*)&stage[0][0] + wave * 2048;   // 8KB per wave
#pragma unroll
    for (int di = 0; di < 4; ++di) {
        f32x4 v = o_acc[di] * inv;
        *(f32x4*)&myOs[lane15 * 68 + di * 16 + quad * 4] = v;   // [q][d]
    }
    float* orow0 = out + ((size_t)(b * T_ + i0)) * C_ + h * 64;
#pragma unroll
    for (int c = 0; c < 4; ++c) {
        const int idx = c * 64 + lane;
        const int t   = idx >> 4;
        const int dc  = (idx & 15) * 4;
        float4 v = *(float4*)&myOs[t * 68 + dc];
        *(float4*)(orow0 + (size_t)t * C_ + dc) = v;
    }
}

// ---------------------------------------------------------------------------
// Launch
// ---------------------------------------------------------------------------
extern "C" void kernel_launch(void* const* d_in, const int* in_sizes, int n_in,
                              void* d_out, int out_size, void* d_ws, size_t ws_size,
                              hipStream_t stream) {
    const float* x  = (const float*)d_in[0];
    const float* Wq = (const float*)d_in[1];
    const float* bq = (const float*)d_in[2];
    const float* Wk = (const float*)d_in[3];
    const float* bk = (const float*)d_in[4];
    const float* Wv = (const float*)d_in[5];
    const float* bv = (const float*)d_in[6];
    float* out = (float*)d_out;

    unsigned short* xb  = (unsigned short*)d_ws;            // 4096*1024
    unsigned short* wb  = xb  + (size_t)B_ * T_ * C_;       // 3*1024*1024
    unsigned short* qb  = wb  + (size_t)3 * C_ * C_;        // chunk-tiled Q
    unsigned short* ktb = qb  + (size_t)B_ * H_ * T_ * D_;  // chunk-tiled K
    unsigned short* vtb = ktb + (size_t)B_ * H_ * T_ * D_;  // permuted chunk-tiled V

    convert_all<<<7168, 256, 0, stream>>>(x, Wq, Wk, Wv, xb, wb);
    gemm_qkv<<<768, 256, 0, stream>>>(xb, wb, bq, bk, bv, qb, ktb, vtb);
    attn<<<1024, 256, 0, stream>>>(qb, ktb, vtb, out);
}

// Round 8
// 144.149 us; speedup vs baseline: 1.0118x; 1.0037x over previous
//
#include <hip/hip_runtime.h>
#include <hip/hip_bf16.h>

// Problem constants
#define B_    2
#define T_    2048
#define C_    1024
#define H_    16
#define D_    64
#define SRCL_ 128

typedef short  short8 __attribute__((ext_vector_type(8)));   // 8 bf16 (4 VGPRs)
typedef float  f32x4  __attribute__((ext_vector_type(4)));
typedef unsigned short ushort4_t __attribute__((ext_vector_type(4)));
typedef unsigned int   uint4v    __attribute__((ext_vector_type(4)));

// Q pre-scale: 0.125 (1/sqrt(64)) * log2(e) so attn can use raw v_exp_f32 (2^x)
#define QSCALE 0.18033688011112042f

__device__ inline unsigned short f2bf(float f) {
    union { float f; unsigned u; } v; v.f = f;
    unsigned r = v.u + 0x7FFFu + ((v.u >> 16) & 1u);   // RNE
    return (unsigned short)(r >> 16);
}

#if __has_builtin(__builtin_amdgcn_exp2f)
#define EXP2F(x) __builtin_amdgcn_exp2f(x)
#else
#define EXP2F(x) exp2f(x)
#endif

// async global->LDS DMA, 16B per lane; LDS dest = uniform base + lane*16
__device__ __forceinline__ void async_ld16(const void* g, void* l) {
    __builtin_amdgcn_global_load_lds(
        (const __attribute__((address_space(1))) unsigned int*)g,
        (__attribute__((address_space(3))) unsigned int*)l, 16, 0, 0);
}

// ---------------------------------------------------------------------------
// Kernel 1: fp32 -> bf16 conversion of x and the three weight matrices.
// ---------------------------------------------------------------------------
__global__ __launch_bounds__(256) void convert_all(
        const float* __restrict__ x,
        const float* __restrict__ wq,
        const float* __restrict__ wk,
        const float* __restrict__ wv,
        unsigned short* __restrict__ xb,
        unsigned short* __restrict__ wb)
{
    const int NX = (B_ * T_ * C_) / 4;
    const int NW = (C_ * C_) / 4;
    int i = blockIdx.x * 256 + threadIdx.x;
    const float4* src;
    ushort4_t* dst;
    if (i < NX)               { src = (const float4*)x;  dst = (ushort4_t*)xb;                }
    else if (i < NX + NW)     { src = (const float4*)wq; dst = (ushort4_t*)wb;                i -= NX; }
    else if (i < NX + 2*NW)   { src = (const float4*)wk; dst = (ushort4_t*)(wb + C_*C_);      i -= NX + NW; }
    else                      { src = (const float4*)wv; dst = (ushort4_t*)(wb + 2*C_*C_);    i -= NX + 2*NW; }
    float4 v = src[i];
    ushort4_t o;
    o.x = f2bf(v.x); o.y = f2bf(v.y); o.z = f2bf(v.z); o.w = f2bf(v.w);
    dst[i] = o;
}

// ---------------------------------------------------------------------------
// Kernel 2: fused QKV GEMM — full 8-phase schedule (m201 template port).
//  - 256x256 tile, BK=64, 512 thr = 8 waves (2M x 4N), per-wave C 128x64.
//  - LDS 128KB: 2 bufs x [A_k0 16K | A_k1 16K | B_k0 16K | B_k1 16K].
//    Slab = one matrix x one 32-wide k-half, [256 rows][32 k] bf16, 64B pitch,
//    XOR-swizzled (write: pre-swizzled global k-seg (l&3)^((l>>3)&3);
//    read: slot quad^((lane15>>1)&3) — HW-verified pair from R7).
//  - 4 phases per K-tile, phase (h,k): quadrant rows h*64, k-half k:
//    {4 (or 4+4) ds_read_b128 | stage 1 future slab (2 gloads) | barrier |
//     setprio(1) 16 MFMA setprio(0) | [vmcnt(4) at tile end] barrier}.
//  - Slab lead = 6 phases; vmcnt(4) ONLY at K-tile boundaries: 2 slabs
//    (4 loads) always in flight, never drained (T3+T4).
//    Region-reuse ledger: k0 slabs last read at phase 1, overwritten at
//    phase 2 two tiles later (one barrier after last read) — verified.
//  - Grid 192 (16 Mt x 12 Nt), XCD-chunked mapping.
//  - Epilogue: R6's proven chunk-tiled Q/K + permuted-V, two 64-row passes.
// ---------------------------------------------------------------------------
__global__ __launch_bounds__(512, 2) void gemm_qkv(
        const unsigned short* __restrict__ xb,   // [4096,1024]
        const unsigned short* __restrict__ wb,   // [3072,1024]
        const float* __restrict__ bq,
        const float* __restrict__ bk,
        const float* __restrict__ bv,
        unsigned short* __restrict__ qo,
        unsigned short* __restrict__ ktp,
        unsigned short* __restrict__ vtp)
{
    __shared__ __align__(16) unsigned short uni[65536];      // 131,072 B

    const int tid  = threadIdx.x;
    const int wave = tid >> 6;           // 0..7
    const int lane = tid & 63;
    const int lane15 = lane & 15;
    const int quad   = lane >> 4;
    const int wm = wave >> 2;            // 0..1  M-half
    const int wn = wave & 3;             // 0..3  N-quarter

    const int bid = blockIdx.x;
    const int xcd = bid & 7;
    const int jj  = bid >> 3;            // 0..23
    const int mt  = xcd * 2 + (jj / 12); // 0..15
    const int nt  = jj % 12;             // 0..11
    const int m0 = mt * 256;
    const int n0 = nt * 256;

    f32x4 acc[8][4];
#pragma unroll
    for (int m = 0; m < 8; ++m)
#pragma unroll
        for (int n = 0; n < 4; ++n)
            acc[m][n] = (f32x4){0.f, 0.f, 0.f, 0.f};

    // ---- staging setup: thread -> (row tid>>2, swizzled k-seg) of a slab
    const int srow  = tid >> 2;                              // 0..127
    const int kseg8 = ((tid & 3) ^ ((tid >> 3) & 3)) * 8;    // pre-swizzle
    const unsigned short* gA = xb + (size_t)(m0 + srow) * 1024 + kseg8;
    const unsigned short* gB = wb + (size_t)(n0 + srow) * 1024 + kseg8;
    char* lbase = (char*)uni + tid * 16;

    // slab s: tile s>>2, j=s&3: 0=A_k0 1=B_k0 2=A_k1 3=B_k1
    auto stage = [&](int s) {
        const int Tt = s >> 2, j = s & 3;
        const unsigned short* g = ((j & 1) ? gB : gA) + Tt * 64 + (j >> 1) * 32;
        char* l = lbase + (Tt & 1) * 65536 + (j & 1) * 32768 + (j >> 1) * 16384;
        async_ld16(g, l);                          // rows 0..127
        async_ld16(g + 128 * 1024, l + 8192);      // rows 128..255
    };

    // prologue: tile0 all 4 slabs + tile1's k0 slabs (lead 6)
#pragma unroll
    for (int s = 0; s < 6; ++s) stage(s);
    __asm__ volatile("s_waitcnt vmcnt(4)\n\ts_barrier" ::: "memory");

    const int swz = (quad ^ ((lane15 >> 1) & 3)) * 16;   // swizzled read slot

    for (int T = 0; T < 16; ++T) {
        const char* bufp = (const char*)uni + (T & 1) * 65536;
        short8 bf[4];
#pragma unroll
        for (int ph = 0; ph < 4; ++ph) {
            const int h = ph & 1, kk = ph >> 1;
            const char* Ap = bufp + kk * 16384;
            const char* Bp = bufp + 32768 + kk * 16384;

            short8 a[4];
#pragma unroll
            for (int mi = 0; mi < 4; ++mi)
                a[mi] = *(const short8*)(Ap + (wm * 128 + h * 64 + mi * 16 + lane15) * 64 + swz);
            if (h == 0) {
#pragma unroll
                for (int ni = 0; ni < 4; ++ni)
                    bf[ni] = *(const short8*)(Bp + (wn * 64 + ni * 16 + lane15) * 64 + swz);
            }

            const int s = T * 4 + ph + 6;
            if (s < 64) stage(s);

            __asm__ volatile("s_barrier" ::: "memory");
            __builtin_amdgcn_s_setprio(1);
#pragma unroll
            for (int mi = 0; mi < 4; ++mi)
#pragma unroll
                for (int ni = 0; ni < 4; ++ni)
                    acc[h * 4 + mi][ni] = __builtin_amdgcn_mfma_f32_16x16x32_bf16(
                        a[mi], bf[ni], acc[h * 4 + mi][ni], 0, 0, 0);
            __builtin_amdgcn_s_setprio(0);

            if (ph == 3)
                __asm__ volatile("s_waitcnt vmcnt(4)\n\ts_barrier" ::: "memory");
            else
                __asm__ volatile("s_barrier" ::: "memory");
        }
    }

    __syncthreads();   // all waves done with tile buffers -> overlay stages

    // ---- epilogue: two 64-row passes per wave (R6 verbatim) ----
    const int colbase = n0 + wn * 64;
    const int which   = colbase >> 10;            // 0=q 1=k 2=v (wave-uniform)
    const int jj0     = colbase & 1023;
    const int h       = jj0 >> 6;
    const float* bias_p = (which == 0 ? bq : (which == 1 ? bk : bv)) + jj0;
    const float oscale  = (which == 0) ? QSCALE : 1.0f;

    unsigned short* stg = &uni[wave * 4160];      // 8 chunks x 520 elems

#pragma unroll
    for (int pass = 0; pass < 2; ++pass) {
        if (which != 2) {
            // Q/K chunk-tiled: pos = (d>>3)*520 + tt*8 + (d&7)
#pragma unroll
            for (int ni = 0; ni < 4; ++ni) {
                const float bias = bias_p[ni * 16 + lane15];
                const int d = ni * 16 + lane15;
                const int dbase = (d >> 3) * 520 + (d & 7);
#pragma unroll
                for (int mi = 0; mi < 4; ++mi)
#pragma unroll
                    for (int r = 0; r < 4; ++r) {
                        const int tt = mi * 16 + quad * 4 + r;
                        stg[dbase + tt * 8] =
                            f2bf((acc[pass * 4 + mi][ni][r] + bias) * oscale);
                    }
            }
        } else {
            // V permuted chunk-tiled: c=((tt>>5)<<2)|((tt>>2)&3),
            // s=(((tt>>4)&1)<<2)|(tt&3)  (matches attn's in-register P frags)
#pragma unroll
            for (int ni = 0; ni < 4; ++ni) {
                const float bias = bias_p[ni * 16 + lane15];
                const int d = ni * 16 + lane15;
#pragma unroll
                for (int mi = 0; mi < 4; ++mi)
#pragma unroll
                    for (int r = 0; r < 4; ++r) {
                        const int tt = mi * 16 + quad * 4 + r;
                        const int c  = ((tt >> 5) << 2) | ((tt >> 2) & 3);
                        const int s  = (((tt >> 4) & 1) << 2) | (tt & 3);
                        stg[c * 520 + d * 8 + s] =
                            f2bf(acc[pass * 4 + mi][ni][r] + bias);
                    }
            }
        }

        const int rowg = m0 + wm * 128 + pass * 64;
        const int bidx = rowg >> 11;
        const int t0   = rowg & 2047;
        const size_t bh = (size_t)bidx * H_ + h;
        unsigned short* gdst =
            (which == 0 ? qo : (which == 1 ? ktp : vtp))
            + bh * (size_t)(T_ * D_) + (t0 >> 6) * 4096;

        // same-wave LDS in-order: no barrier needed before reading own stage
#pragma unroll
        for (int c = 0; c < 8; ++c) {
            *(short8*)&gdst[(c * 64 + lane) * 8] = *(const short8*)&stg[c * 520 + lane * 8];
        }
    }
}

// ---------------------------------------------------------------------------
// Kernel 3: flash attention (round-1 config, best measured: 143.7us total).
// Block = (bh, 64 q-rows); 4 waves x 16 q-rows share staged K/V tiles.
// P stays entirely in registers: packed bf16 words feed PV's B operand
// directly; V's global layout (gemm epilogue) was permuted to match.
// LDS = 32KB -> 4 blocks/CU resident.
// ---------------------------------------------------------------------------
__global__ __launch_bounds__(256, 4) void attn(
        const unsigned short* __restrict__ qg,   // chunk-tiled Q (pre-scaled)
        const unsigned short* __restrict__ kg,   // chunk-tiled K
        const unsigned short* __restrict__ vg,   // permuted chunk-tiled V
        float* __restrict__ out)                 // [B,T,C] fp32
{
    __shared__ __align__(16) unsigned short stage[2][8192];  // [buf][K 8KB | V 8KB]

    const int tid  = threadIdx.x;
    const int wave = tid >> 6;
    const int lane = tid & 63;
    const int lane15 = lane & 15;
    const int quad   = lane >> 4;

    const int bh = blockIdx.x & 31;
    const int a  = 31 - (blockIdx.x >> 5);       // heavy q-blocks first
    const int b  = bh >> 4;
    const int h  = bh & 15;
    const int i0 = a * 64 + wave * 16;           // this wave's q rows

    const unsigned short* Q  = qg + (size_t)bh * T_ * D_;
    const unsigned short* KT = kg + (size_t)bh * T_ * D_;
    const unsigned short* VT = vg + (size_t)bh * T_ * D_;

    // Q fragments from chunk-tiled layout: [qtile a][d-chunk][t][8d]
    const int qrow = wave * 16 + lane15;
    const short8 qf0 = *(const short8*)&Q[a * 4096 + quad * 512 + qrow * 8];
    const short8 qf1 = *(const short8*)&Q[a * 4096 + (4 + quad) * 512 + qrow * 8];

    f32x4 o_acc[4];
#pragma unroll
    for (int di = 0; di < 4; ++di) o_acc[di] = (f32x4){0.f, 0.f, 0.f, 0.f};
    float l_p = 0.f;

    const int ntiles = min(a + 3, 32);           // key tiles for this q-block
    const int limit  = i0 + lane15 + SRCL_;

    // DMA of one 16KB tile-pair: 16 x 1KB instrs; wave w issues instrs 4w..4w+3
    const int ib = wave * 4;
    const int loff = lane * 8;

    // prologue: tile 0 -> buf 0
#pragma unroll
    for (int c = 0; c < 4; ++c) {
        const int i = ib + c;
        const unsigned short* src = (i < 8) ? &KT[i * 512 + loff]
                                            : &VT[(i - 8) * 512 + loff];
        async_ld16(src, &stage[0][i * 512]);
    }

    for (int it = 0; it < ntiles; ++it) {
        // own 4 DMAs done + all waves past compute of the other buffer
        __asm__ volatile("s_waitcnt vmcnt(0)\n\ts_barrier" ::: "memory");

        if (it + 1 < ntiles) {
            unsigned short* nb = &stage[(it + 1) & 1][0];
            const size_t tb = (size_t)(it + 1) * 4096;
#pragma unroll
            for (int c = 0; c < 4; ++c) {
                const int i = ib + c;
                const unsigned short* src = (i < 8) ? &KT[tb + i * 512 + loff]
                                                    : &VT[tb + (i - 8) * 512 + loff];
                async_ld16(src, &nb[i * 512]);
            }
        }

        const unsigned short* sb = &stage[it & 1][0];
        const int j0 = it << 6;

        // ---- S^T = K Q^T
        f32x4 sv[4];
#pragma unroll
        for (int ni = 0; ni < 4; ++ni) {
            const short8 kf0 = *(const short8*)&sb[quad * 512 + (ni * 16 + lane15) * 8];
            const short8 kf1 = *(const short8*)&sb[(4 + quad) * 512 + (ni * 16 + lane15) * 8];
            f32x4 t = (f32x4){0.f, 0.f, 0.f, 0.f};
            t = __builtin_amdgcn_mfma_f32_16x16x32_bf16(kf0, qf0, t, 0, 0, 0);
            t = __builtin_amdgcn_mfma_f32_16x16x32_bf16(kf1, qf1, t, 0, 0, 0);
            sv[ni] = t;
        }

        if (j0 + 63 > i0 + SRCL_) {               // boundary tiles only
#pragma unroll
            for (int ni = 0; ni < 4; ++ni)
#pragma unroll
                for (int r = 0; r < 4; ++r) {
                    const int key = j0 + ni * 16 + quad * 4 + r;
                    if (key > limit) sv[ni][r] = -INFINITY;
                }
        }

        // ---- softmax numerators -> packed bf16 P fragments (in registers)
        // lane (quad,lane15) holds P^T[key = j0 + ni*16 + 4*quad + r][q=lane15];
        // pf0 element e -> key 16*(e>>2) + 4*quad + (e&3), pf1 -> +32.
        // V was stored (gemm epilogue) with exactly this t->(chunk,slot) map.
        float lacc = 0.f;
        unsigned pw[8];
#pragma unroll
        for (int ni = 0; ni < 4; ++ni) {
            const float p0 = EXP2F(sv[ni][0]);
            const float p1 = EXP2F(sv[ni][1]);
            const float p2 = EXP2F(sv[ni][2]);
            const float p3 = EXP2F(sv[ni][3]);
            lacc += (p0 + p1) + (p2 + p3);
            const unsigned u0 = __float_as_uint(p0) + 0x8000u;
            const unsigned u1 = __float_as_uint(p1) + 0x8000u;
            const unsigned u2 = __float_as_uint(p2) + 0x8000u;
            const unsigned u3 = __float_as_uint(p3) + 0x8000u;
            pw[ni * 2]     = __builtin_amdgcn_perm(u1, u0, 0x07060302);
            pw[ni * 2 + 1] = __builtin_amdgcn_perm(u3, u2, 0x07060302);
        }
        l_p += lacc;

        const uint4v w0 = {pw[0], pw[1], pw[2], pw[3]};
        const uint4v w1 = {pw[4], pw[5], pw[6], pw[7]};
        const short8 pf0 = __builtin_bit_cast(short8, w0);
        const short8 pf1 = __builtin_bit_cast(short8, w1);

        // ---- V fragments + PV
#pragma unroll
        for (int di = 0; di < 4; ++di) {
            const short8 vf0 = *(const short8*)&sb[4096 + quad * 512 + (di * 16 + lane15) * 8];
            const short8 vf1 = *(const short8*)&sb[4096 + (4 + quad) * 512 + (di * 16 + lane15) * 8];
            o_acc[di] = __builtin_amdgcn_mfma_f32_16x16x32_bf16(vf0, pf0, o_acc[di], 0, 0, 0);
            o_acc[di] = __builtin_amdgcn_mfma_f32_16x16x32_bf16(vf1, pf1, o_acc[di], 0, 0, 0);
        }
    }

    __syncthreads();   // stage reuse as O scratch across waves

    float l0s = l_p + __shfl_xor(l_p, 16);
    const float inv = 1.0f / (l0s + __shfl_xor(l0s, 32));

    float* myOs = (float*)&stage[0][0] + wave * 2048;   // 8KB per wave
#pragma unroll
    for (int di = 0; di < 4; ++di) {
        f32x4 v = o_acc[di] * inv;
        *(f32x4*)&myOs[lane15 * 68 + di * 16 + quad * 4] = v;   // [q][d]
    }
    float* orow0 = out + ((size_t)(b * T_ + i0)) * C_ + h * 64;
#pragma unroll
    for (int c = 0; c < 4; ++c) {
        const int idx = c * 64 + lane;
        const int t   = idx >> 4;
        const int dc  = (idx & 15) * 4;
        float4 v = *(float4*)&myOs[t * 68 + dc];
        *(float4*)(orow0 + (size_t)t * C_ + dc) = v;
    }
}

// ---------------------------------------------------------------------------
// Launch
// ---------------------------------------------------------------------------
extern "C" void kernel_launch(void* const* d_in, const int* in_sizes, int n_in,
                              void* d_out, int out_size, void* d_ws, size_t ws_size,
                              hipStream_t stream) {
    const float* x  = (const float*)d_in[0];
    const float* Wq = (const float*)d_in[1];
    const float* bq = (const float*)d_in[2];
    const float* Wk = (const float*)d_in[3];
    const float* bk = (const float*)d_in[4];
    const float* Wv = (const float*)d_in[5];
    const float* bv = (const float*)d_in[6];
    float* out = (float*)d_out;

    unsigned short* xb  = (unsigned short*)d_ws;            // 4096*1024
    unsigned short* wb  = xb  + (size_t)B_ * T_ * C_;       // 3*1024*1024
    unsigned short* qb  = wb  + (size_t)3 * C_ * C_;        // chunk-tiled Q
    unsigned short* ktb = qb  + (size_t)B_ * H_ * T_ * D_;  // chunk-tiled K
    unsigned short* vtb = ktb + (size_t)B_ * H_ * T_ * D_;  // permuted chunk-tiled V

    convert_all<<<7168, 256, 0, stream>>>(x, Wq, Wk, Wv, xb, wb);
    gemm_qkv<<<192, 512, 0, stream>>>(xb, wb, bq, bk, bv, qb, ktb, vtb);
    attn<<<1024, 256, 0, stream>>>(qb, ktb, vtb, out);
}